// Round 1
// baseline (568.855 us; speedup 1.0000x reference)
//
#include <hip/hip_runtime.h>

#define HH 128
#define RNUM 8
#define CC 40
#define CAP 64                // padded edge slots per dst (P(deg>64) ~ 1e-19)
#define LDA 136               // LDS row stride (bf16): 128 + 8 pad
#define SRCMASK 0x7FFFFFF

typedef __attribute__((ext_vector_type(8))) short short8;
typedef __attribute__((ext_vector_type(4))) float floatx4;

__device__ __forceinline__ float u2f(unsigned u) {
    union { unsigned u; float f; } c;
    c.u = u;
    return c.f;
}
__device__ __forceinline__ unsigned short f2bf(float f) {
    union { float f; unsigned u; } c;
    c.f = f;
    return (unsigned short)((c.u + 0x7FFFu + ((c.u >> 16) & 1u)) >> 16);
}

// ---------------- fused preprocessing: edge bucketing + W1 fp32->bf16 cast + B-stack transpose ----
// blocks [0, fillB): bucket edges   elist[d*64+p] = (rel<<27)|src
// blocks [fillB, fillB+castB): cast W1 (R*N*H fp32) -> W1b (bf16), 8 elems/thread
// blocks [fillB+castB, +288): Bt[c][n][k] = bf16(Bc[k][n]), c0=root2 c1..8=W2
__global__ void prep_kernel(const int* __restrict__ src, const int* __restrict__ dst,
                            const int* __restrict__ et, int* __restrict__ deg,
                            int* __restrict__ elist, int E,
                            const float* __restrict__ W1, unsigned short* __restrict__ W1b,
                            size_t castElems,
                            const float* __restrict__ root2, const float* __restrict__ W2,
                            unsigned short* __restrict__ Bt, int fillB, int castB) {
    int b = blockIdx.x;
    if (b < fillB) {
        int e = b * 256 + threadIdx.x;
        if (e < E) {
            int d = dst[e];
            int p = atomicAdd(&deg[d], 1);
            if (p < CAP) elist[(size_t)d * CAP + p] = (int)(((unsigned)et[e] << 27) | (unsigned)src[e]);
        }
    } else if (b < fillB + castB) {
        size_t i8 = ((size_t)(b - fillB) * 256 + threadIdx.x) * 8;
        if (i8 < castElems) {
            float4 f0 = *(const float4*)(W1 + i8);
            float4 f1 = *(const float4*)(W1 + i8 + 4);
            uint4 o;
            o.x = (unsigned)f2bf(f0.x) | ((unsigned)f2bf(f0.y) << 16);
            o.y = (unsigned)f2bf(f0.z) | ((unsigned)f2bf(f0.w) << 16);
            o.z = (unsigned)f2bf(f1.x) | ((unsigned)f2bf(f1.y) << 16);
            o.w = (unsigned)f2bf(f1.z) | ((unsigned)f2bf(f1.w) << 16);
            *(uint4*)(W1b + i8) = o;
        }
    } else {
        int bid = b - fillB - castB;
        int c = bid >> 5;
        int id = (bid & 31) * 256 + threadIdx.x;
        int n = id >> 6, kp = id & 63;
        const float* B = (c == 0) ? root2 : W2 + (size_t)(c - 1) * HH * HH;
        float g0 = B[(2 * kp) * HH + n];
        float g1 = B[(2 * kp + 1) * HH + n];
        unsigned v = (unsigned)f2bf(g0) | ((unsigned)f2bf(g1) << 16);
        *(unsigned*)(Bt + (size_t)c * HH * HH + n * HH + 2 * kp) = v;
    }
}

// ---------------- layer 1: wave per dst; edge list lives in wave registers ----------------
// h[d] = relu( sum_r (1/c_r) * sum_{e in (d,r)} W1b[r, src_e] + root1[d] + b1 )
// W1 rows now bf16: one uint4 (16 B) per lane per edge (quad covers 256 B row)
__global__ void gather1_kernel(const int* __restrict__ deg, const int* __restrict__ elist,
                               const unsigned short* __restrict__ W1b, const float* __restrict__ root1,
                               const float* __restrict__ b1, unsigned short* __restrict__ hbf,
                               int Nn) {
    int w = (blockIdx.x * blockDim.x + threadIdx.x) >> 6;
    if (w >= Nn) return;
    int lane = threadIdx.x & 63;
    int qid = lane >> 4, cl = lane & 15;      // quad gathers one 256 B bf16 row
    int dd = min(deg[w], CAP);
    int pk = elist[(size_t)w * CAP + lane];   // one coalesced 256 B load: slot per lane
    int myrel = (lane < dd) ? (int)((unsigned)pk >> 27) : 8;

    // per-relation counts via ballot; lane r holds 1/max(1,c_r)
    float myinv = 1.0f;
#pragma unroll
    for (int r = 0; r < 8; ++r) {
        unsigned long long m = __ballot(myrel == r);
        int c = __popcll(m);
        if (lane == r) myinv = 1.0f / fmaxf(1.0f, (float)c);
    }

    float s0[8] = {0.f, 0.f, 0.f, 0.f, 0.f, 0.f, 0.f, 0.f};
    float s1[8] = {0.f, 0.f, 0.f, 0.f, 0.f, 0.f, 0.f, 0.f};
    float s2[8] = {0.f, 0.f, 0.f, 0.f, 0.f, 0.f, 0.f, 0.f};
    float s3[8] = {0.f, 0.f, 0.f, 0.f, 0.f, 0.f, 0.f, 0.f};

    // group g = edges 4g..4g+3, quad k takes edge 4g+k; uniform trip count, shuffles
    // outside divergence, only the loads predicated.
#define GRP(G, S)                                                                 \
    {                                                                             \
        int j = ((G) << 2) + qid;                                                 \
        int jj = min(j, dd - 1);                                                  \
        int pkj = __shfl(pk, jj);                                                 \
        int rr = (int)((unsigned)pkj >> 27);                                      \
        float wt = __shfl(myinv, rr);                                             \
        int ss = pkj & SRCMASK;                                                   \
        const unsigned short* p = W1b + ((size_t)rr * Nn + ss) * HH + cl * 8;     \
        if (j < dd) {                                                             \
            uint4 v = *(const uint4*)p;                                           \
            S[0] += u2f(v.x << 16) * wt; S[1] += u2f(v.x & 0xFFFF0000u) * wt;     \
            S[2] += u2f(v.y << 16) * wt; S[3] += u2f(v.y & 0xFFFF0000u) * wt;     \
            S[4] += u2f(v.z << 16) * wt; S[5] += u2f(v.z & 0xFFFF0000u) * wt;     \
            S[6] += u2f(v.w << 16) * wt; S[7] += u2f(v.w & 0xFFFF0000u) * wt;     \
        }                                                                         \
    }

    int ng = (dd + 3) >> 2;                   // number of 4-edge groups (uniform)
    int g = 0;
    for (; g + 3 < ng; g += 4) {              // 4 streams -> 4 loads in flight/lane
        GRP(g, s0);
        GRP(g + 1, s1);
        GRP(g + 2, s2);
        GRP(g + 3, s3);
    }
    for (; g < ng; ++g) GRP(g, s0);
#undef GRP

#pragma unroll
    for (int k = 0; k < 8; ++k) {
        s0[k] += s1[k] + s2[k] + s3[k];
        s0[k] += __shfl_xor(s0[k], 16);
        s0[k] += __shfl_xor(s0[k], 32);
    }

    if (qid == 0) {
        const float* rp = root1 + (size_t)w * HH + cl * 8;
        float4 r0 = *(const float4*)rp;
        float4 r1 = *(const float4*)(rp + 4);
        float4 c0 = *(const float4*)(b1 + cl * 8);
        float4 c1 = *(const float4*)(b1 + cl * 8 + 4);
        float o[8];
        o[0] = fmaxf(s0[0] + r0.x + c0.x, 0.f); o[1] = fmaxf(s0[1] + r0.y + c0.y, 0.f);
        o[2] = fmaxf(s0[2] + r0.z + c0.z, 0.f); o[3] = fmaxf(s0[3] + r0.w + c0.w, 0.f);
        o[4] = fmaxf(s0[4] + r1.x + c1.x, 0.f); o[5] = fmaxf(s0[5] + r1.y + c1.y, 0.f);
        o[6] = fmaxf(s0[6] + r1.z + c1.z, 0.f); o[7] = fmaxf(s0[7] + r1.w + c1.w, 0.f);
        ushort4 pk0, pk1;
        pk0.x = f2bf(o[0]); pk0.y = f2bf(o[1]); pk0.z = f2bf(o[2]); pk0.w = f2bf(o[3]);
        pk1.x = f2bf(o[4]); pk1.y = f2bf(o[5]); pk1.z = f2bf(o[6]); pk1.w = f2bf(o[7]);
        unsigned short* hp = hbf + (size_t)w * HH + cl * 8;
        *(ushort4*)hp = pk0;
        *(ushort4*)(hp + 4) = pk1;
    }
}

// ---------------- layer-2 aggregation: wave per (dst, rel-half); ballot-driven ----------------
// aggr[d*8+r] = mean_{e in (d,r)} hbf[src_e]   (zeros when empty)
__global__ void agg_kernel(const int* __restrict__ deg, const int* __restrict__ elist,
                           const unsigned short* __restrict__ hbf,
                           unsigned short* __restrict__ aggr, int Nn) {
    int w = (blockIdx.x * blockDim.x + threadIdx.x) >> 6;
    int d = w >> 1;
    if (d >= Nn) return;
    int half = w & 1;
    int lane = threadIdx.x & 63;
    int qid = lane >> 4, cl = lane & 15;      // quad gathers one 256 B bf16 row
    int dd = min(deg[d], CAP);
    int pk = elist[(size_t)d * CAP + lane];
    int myrel = (lane < dd) ? (int)((unsigned)pk >> 27) : 8;

#define ACC8(V, S)                                                 \
    {                                                              \
        S[0] += u2f(V.x << 16); S[1] += u2f(V.x & 0xFFFF0000u);    \
        S[2] += u2f(V.y << 16); S[3] += u2f(V.y & 0xFFFF0000u);    \
        S[4] += u2f(V.z << 16); S[5] += u2f(V.z & 0xFFFF0000u);    \
        S[6] += u2f(V.w << 16); S[7] += u2f(V.w & 0xFFFF0000u);    \
    }

#pragma unroll
    for (int ri = 0; ri < 4; ++ri) {
        int r = half * 4 + ri;
        unsigned long long m = __ballot(myrel == r);
        int c = __popcll(m);
        float inv = 1.0f / fmaxf(1.0f, (float)c);
        float s[8] = {0.f, 0.f, 0.f, 0.f, 0.f, 0.f, 0.f, 0.f};
        int idx = 0;
        while (m) {                            // uniform mask walk; quad (idx&3) loads
            int j = __ffsll((unsigned long long)m) - 1;
            m &= m - 1;
            int pkj = __shfl(pk, j);           // uniform src lane, all lanes active
            if ((idx & 3) == qid) {
                int ss = pkj & SRCMASK;
                uint4 v = *(const uint4*)(hbf + (size_t)ss * HH + cl * 8);
                ACC8(v, s);
            }
            ++idx;
        }
#pragma unroll
        for (int k = 0; k < 8; ++k) {
            s[k] += __shfl_xor(s[k], 16);
            s[k] += __shfl_xor(s[k], 32);
        }
        if (qid == 0) {
            ushort4 p0, p1;
            p0.x = f2bf(s[0] * inv); p0.y = f2bf(s[1] * inv);
            p0.z = f2bf(s[2] * inv); p0.w = f2bf(s[3] * inv);
            p1.x = f2bf(s[4] * inv); p1.y = f2bf(s[5] * inv);
            p1.z = f2bf(s[6] * inv); p1.w = f2bf(s[7] * inv);
            unsigned short* ap = aggr + ((size_t)d * RNUM + r) * HH + cl * 8;
            *(ushort4*)ap = p0;
            *(ushort4*)(ap + 4) = p1;
        }
    }
#undef ACC8
}

// ---------------- GEMM over 9 K-chunks (streaming A) + fused final linear ----------------
__global__ __launch_bounds__(256, 3) void gemm9_kernel(
    const unsigned short* __restrict__ hbf, const unsigned short* __restrict__ aggr,
    const unsigned short* __restrict__ Bt, const float* __restrict__ b2,
    const float* __restrict__ lin_w, const float* __restrict__ lin_b,
    float* __restrict__ out, int Nn) {
    __shared__ unsigned short As[64 * LDA];
    __shared__ unsigned short Bs[128 * LDA];
    const int tid = threadIdx.x;
    const int lane = tid & 63, wv = tid >> 6;
    const int quad = lane >> 4, l16 = lane & 15;
    const int mr = wv & 1, nc = wv >> 1;
    const int m0 = blockIdx.x * 64;

    floatx4 acc[2][4];
#pragma unroll
    for (int a = 0; a < 2; ++a)
#pragma unroll
        for (int bb = 0; bb < 4; ++bb) acc[a][bb] = (floatx4){0.f, 0.f, 0.f, 0.f};

    for (int c = 0; c < 9; ++c) {
        __syncthreads();
        const unsigned short* Bsrc = Bt + (size_t)c * HH * HH;
#pragma unroll
        for (int it = 0; it < 8; ++it) {
            int id = tid + it * 256;
            int rw = id >> 4, c8 = id & 15;
            *(uint4*)(Bs + rw * LDA + c8 * 8) = *(const uint4*)(Bsrc + rw * HH + c8 * 8);
        }
#pragma unroll
        for (int it = 0; it < 4; ++it) {
            int id = tid + it * 256;
            int rw = id >> 4, c8 = id & 15;
            uint4 v = make_uint4(0, 0, 0, 0);
            if (m0 + rw < Nn) {
                const unsigned short* Asrc =
                    (c == 0) ? (hbf + (size_t)(m0 + rw) * HH)
                             : (aggr + ((size_t)(m0 + rw) * RNUM + (c - 1)) * HH);
                v = *(const uint4*)(Asrc + c8 * 8);
            }
            *(uint4*)(As + rw * LDA + c8 * 8) = v;
        }
        __syncthreads();
#pragma unroll
        for (int ks = 0; ks < 4; ++ks) {
            short8 a0 = *(const short8*)(As + (mr * 32 + l16) * LDA + ks * 32 + quad * 8);
            short8 a1 = *(const short8*)(As + (mr * 32 + 16 + l16) * LDA + ks * 32 + quad * 8);
#pragma unroll
            for (int nf = 0; nf < 4; ++nf) {
                short8 b = *(const short8*)(Bs + (nc * 64 + nf * 16 + l16) * LDA + ks * 32 + quad * 8);
                acc[0][nf] = __builtin_amdgcn_mfma_f32_16x16x32_bf16(a0, b, acc[0][nf], 0, 0, 0);
                acc[1][nf] = __builtin_amdgcn_mfma_f32_16x16x32_bf16(a1, b, acc[1][nf], 0, 0, 0);
            }
        }
    }

    // epilogue 1: relu(C + b2) -> As as bf16 (C/D layout: col=lane&15, row=quad*4+reg)
    __syncthreads();
#pragma unroll
    for (int mf = 0; mf < 2; ++mf)
#pragma unroll
        for (int nf = 0; nf < 4; ++nf) {
            int gcol = nc * 64 + nf * 16 + l16;
            float bb = b2[gcol];
#pragma unroll
            for (int rg = 0; rg < 4; ++rg) {
                int row = mr * 32 + mf * 16 + quad * 4 + rg;
                float v = fmaxf(acc[mf][nf][rg] + bb, 0.f);
                As[row * LDA + gcol] = f2bf(v);
            }
        }
    // stage lin_w^T (bf16) into Bs rows 0..39
    for (int it = 0; it < 20; ++it) {
        int id = tid + it * 256;
        int n = id >> 7, k = id & 127;
        Bs[n * LDA + k] = f2bf(lin_w[k * CC + n]);
    }
    __syncthreads();

    floatx4 acc2[3];
#pragma unroll
    for (int nf = 0; nf < 3; ++nf) acc2[nf] = (floatx4){0.f, 0.f, 0.f, 0.f};
#pragma unroll
    for (int ks = 0; ks < 4; ++ks) {
        short8 a = *(const short8*)(As + (wv * 16 + l16) * LDA + ks * 32 + quad * 8);
#pragma unroll
        for (int nf = 0; nf < 3; ++nf) {
            short8 b = *(const short8*)(Bs + (nf * 16 + l16) * LDA + ks * 32 + quad * 8);
            acc2[nf] = __builtin_amdgcn_mfma_f32_16x16x32_bf16(a, b, acc2[nf], 0, 0, 0);
        }
    }
#pragma unroll
    for (int nf = 0; nf < 3; ++nf) {
        int col = nf * 16 + l16;
        if (col < CC) {
            float lb = lin_b[col];
#pragma unroll
            for (int rg = 0; rg < 4; ++rg) {
                int grow = m0 + wv * 16 + quad * 4 + rg;
                if (grow < Nn) out[(size_t)grow * CC + col] = acc2[nf][rg] + lb;
            }
        }
    }
}

// ---------------- launcher ----------------

extern "C" void kernel_launch(void* const* d_in, const int* in_sizes, int n_in,
                              void* d_out, int out_size, void* d_ws, size_t ws_size,
                              hipStream_t stream) {
    const int* ei      = (const int*)d_in[0];
    const int* et      = (const int*)d_in[1];
    const float* W1    = (const float*)d_in[2];
    const float* root1 = (const float*)d_in[3];
    const float* b1    = (const float*)d_in[4];
    const float* W2    = (const float*)d_in[5];
    const float* root2 = (const float*)d_in[6];
    const float* b2    = (const float*)d_in[7];
    const float* lw    = (const float*)d_in[8];
    const float* lb    = (const float*)d_in[9];
    float* out = (float*)d_out;

    const int E = in_sizes[1];
    const int N = in_sizes[3] / HH;

    // ws: deg[N] | elist[N*CAP] ints; then hbf | W1b | Bt | aggr (bf16)  (~231 MB)
    int* deg   = (int*)d_ws;
    int* elist = deg + N;
    size_t iofs = (size_t)N + (size_t)N * CAP;
    iofs = (iofs + 3) & ~(size_t)3;                     // 16B align
    unsigned short* hbf  = (unsigned short*)((int*)d_ws + iofs);
    unsigned short* W1b  = hbf + (size_t)N * HH;
    unsigned short* Bt   = W1b + (size_t)N * RNUM * HH;
    unsigned short* aggr = Bt + (size_t)9 * HH * HH;

    const int* src = ei;
    const int* dst = ei + E;

    const size_t castElems = (size_t)N * RNUM * HH;
    const int fillB = (E + 255) / 256;
    const int castB = (int)((castElems / 8 + 255) / 256);

    hipMemsetAsync(deg, 0, (size_t)N * sizeof(int), stream);
    prep_kernel<<<fillB + castB + 9 * 32, 256, 0, stream>>>(
        src, dst, et, deg, elist, E, W1, W1b, castElems, root2, W2, Bt, fillB, castB);

    gather1_kernel<<<(N * 64 + 255) / 256, 256, 0, stream>>>(deg, elist, W1b, root1, b1, hbf, N);
    agg_kernel<<<(N * 2 * 64 + 255) / 256, 256, 0, stream>>>(deg, elist, hbf, aggr, N);
    gemm9_kernel<<<(N + 63) / 64, 256, 0, stream>>>(hbf, aggr, Bt, b2, lw, lb, out, N);
}

// Round 2
// 558.313 us; speedup vs baseline: 1.0189x; 1.0189x over previous
//
#include <hip/hip_runtime.h>

#define HH 128
#define RNUM 8
#define CC 40
#define CAP 64                // padded edge slots per dst (P(deg>64) ~ 1e-19)
#define LDA 136               // LDS row stride (bf16): 128 + 8 pad
#define SRCMASK 0x7FFFFFF
#define DEGSTR 16             // deg counter stride in ints: 1 counter per 64-B line (atomic false-sharing fix)

typedef __attribute__((ext_vector_type(8))) short short8;
typedef __attribute__((ext_vector_type(4))) float floatx4;

__device__ __forceinline__ float u2f(unsigned u) {
    union { unsigned u; float f; } c;
    c.u = u;
    return c.f;
}
__device__ __forceinline__ unsigned short f2bf(float f) {
    union { float f; unsigned u; } c;
    c.f = f;
    return (unsigned short)((c.u + 0x7FFFu + ((c.u >> 16) & 1u)) >> 16);
}

// ---------------- fused preprocessing: edge bucketing + W1 fp32->bf16 cast + B-stack transpose ----
// blocks [0, fillB): bucket edges   elist[d*64+p] = (rel<<27)|src
// blocks [fillB, fillB+castB): cast W1 (R*N*H fp32) -> W1b (bf16), 8 elems/thread
// blocks [fillB+castB, +288): Bt[c][n][k] = bf16(Bc[k][n]), c0=root2 c1..8=W2
__global__ void prep_kernel(const int* __restrict__ src, const int* __restrict__ dst,
                            const int* __restrict__ et, int* __restrict__ deg,
                            int* __restrict__ elist, int E,
                            const float* __restrict__ W1, unsigned short* __restrict__ W1b,
                            size_t castElems,
                            const float* __restrict__ root2, const float* __restrict__ W2,
                            unsigned short* __restrict__ Bt, int fillB, int castB) {
    int b = blockIdx.x;
    if (b < fillB) {
        int e = b * 256 + threadIdx.x;
        if (e < E) {
            int d = dst[e];
            int p = atomicAdd(&deg[(size_t)d * DEGSTR], 1);   // padded: no false sharing
            if (p < CAP) elist[(size_t)d * CAP + p] = (int)(((unsigned)et[e] << 27) | (unsigned)src[e]);
        }
    } else if (b < fillB + castB) {
        size_t i8 = ((size_t)(b - fillB) * 256 + threadIdx.x) * 8;
        if (i8 < castElems) {
            float4 f0 = *(const float4*)(W1 + i8);
            float4 f1 = *(const float4*)(W1 + i8 + 4);
            uint4 o;
            o.x = (unsigned)f2bf(f0.x) | ((unsigned)f2bf(f0.y) << 16);
            o.y = (unsigned)f2bf(f0.z) | ((unsigned)f2bf(f0.w) << 16);
            o.z = (unsigned)f2bf(f1.x) | ((unsigned)f2bf(f1.y) << 16);
            o.w = (unsigned)f2bf(f1.z) | ((unsigned)f2bf(f1.w) << 16);
            *(uint4*)(W1b + i8) = o;
        }
    } else {
        int bid = b - fillB - castB;
        int c = bid >> 5;
        int id = (bid & 31) * 256 + threadIdx.x;
        int n = id >> 6, kp = id & 63;
        const float* B = (c == 0) ? root2 : W2 + (size_t)(c - 1) * HH * HH;
        float g0 = B[(2 * kp) * HH + n];
        float g1 = B[(2 * kp + 1) * HH + n];
        unsigned v = (unsigned)f2bf(g0) | ((unsigned)f2bf(g1) << 16);
        *(unsigned*)(Bt + (size_t)c * HH * HH + n * HH + 2 * kp) = v;
    }
}

// ---------------- layer 1: wave per dst; edge list lives in wave registers ----------------
// h[d] = relu( sum_r (1/c_r) * sum_{e in (d,r)} W1b[r, src_e] + root1[d] + b1 )
// W1 rows now bf16: one uint4 (16 B) per lane per edge (quad covers 256 B row)
__global__ void gather1_kernel(const int* __restrict__ deg, const int* __restrict__ elist,
                               const unsigned short* __restrict__ W1b, const float* __restrict__ root1,
                               const float* __restrict__ b1, unsigned short* __restrict__ hbf,
                               int Nn) {
    int w = (blockIdx.x * blockDim.x + threadIdx.x) >> 6;
    if (w >= Nn) return;
    int lane = threadIdx.x & 63;
    int qid = lane >> 4, cl = lane & 15;      // quad gathers one 256 B bf16 row
    int dd = min(deg[(size_t)w * DEGSTR], CAP);
    int pk = elist[(size_t)w * CAP + lane];   // one coalesced 256 B load: slot per lane
    int myrel = (lane < dd) ? (int)((unsigned)pk >> 27) : 8;

    // per-relation counts via ballot; lane r holds 1/max(1,c_r)
    float myinv = 1.0f;
#pragma unroll
    for (int r = 0; r < 8; ++r) {
        unsigned long long m = __ballot(myrel == r);
        int c = __popcll(m);
        if (lane == r) myinv = 1.0f / fmaxf(1.0f, (float)c);
    }

    float s0[8] = {0.f, 0.f, 0.f, 0.f, 0.f, 0.f, 0.f, 0.f};
    float s1[8] = {0.f, 0.f, 0.f, 0.f, 0.f, 0.f, 0.f, 0.f};
    float s2[8] = {0.f, 0.f, 0.f, 0.f, 0.f, 0.f, 0.f, 0.f};
    float s3[8] = {0.f, 0.f, 0.f, 0.f, 0.f, 0.f, 0.f, 0.f};

    // group g = edges 4g..4g+3, quad k takes edge 4g+k; uniform trip count, shuffles
    // outside divergence, only the loads predicated.
#define GRP(G, S)                                                                 \
    {                                                                             \
        int j = ((G) << 2) + qid;                                                 \
        int jj = min(j, dd - 1);                                                  \
        int pkj = __shfl(pk, jj);                                                 \
        int rr = (int)((unsigned)pkj >> 27);                                      \
        float wt = __shfl(myinv, rr);                                             \
        int ss = pkj & SRCMASK;                                                   \
        const unsigned short* p = W1b + ((size_t)rr * Nn + ss) * HH + cl * 8;     \
        if (j < dd) {                                                             \
            uint4 v = *(const uint4*)p;                                           \
            S[0] += u2f(v.x << 16) * wt; S[1] += u2f(v.x & 0xFFFF0000u) * wt;     \
            S[2] += u2f(v.y << 16) * wt; S[3] += u2f(v.y & 0xFFFF0000u) * wt;     \
            S[4] += u2f(v.z << 16) * wt; S[5] += u2f(v.z & 0xFFFF0000u) * wt;     \
            S[6] += u2f(v.w << 16) * wt; S[7] += u2f(v.w & 0xFFFF0000u) * wt;     \
        }                                                                         \
    }

    int ng = (dd + 3) >> 2;                   // number of 4-edge groups (uniform)
    int g = 0;
    for (; g + 3 < ng; g += 4) {              // 4 streams -> 4 loads in flight/lane
        GRP(g, s0);
        GRP(g + 1, s1);
        GRP(g + 2, s2);
        GRP(g + 3, s3);
    }
    for (; g < ng; ++g) GRP(g, s0);
#undef GRP

#pragma unroll
    for (int k = 0; k < 8; ++k) {
        s0[k] += s1[k] + s2[k] + s3[k];
        s0[k] += __shfl_xor(s0[k], 16);
        s0[k] += __shfl_xor(s0[k], 32);
    }

    if (qid == 0) {
        const float* rp = root1 + (size_t)w * HH + cl * 8;
        float4 r0 = *(const float4*)rp;
        float4 r1 = *(const float4*)(rp + 4);
        float4 c0 = *(const float4*)(b1 + cl * 8);
        float4 c1 = *(const float4*)(b1 + cl * 8 + 4);
        float o[8];
        o[0] = fmaxf(s0[0] + r0.x + c0.x, 0.f); o[1] = fmaxf(s0[1] + r0.y + c0.y, 0.f);
        o[2] = fmaxf(s0[2] + r0.z + c0.z, 0.f); o[3] = fmaxf(s0[3] + r0.w + c0.w, 0.f);
        o[4] = fmaxf(s0[4] + r1.x + c1.x, 0.f); o[5] = fmaxf(s0[5] + r1.y + c1.y, 0.f);
        o[6] = fmaxf(s0[6] + r1.z + c1.z, 0.f); o[7] = fmaxf(s0[7] + r1.w + c1.w, 0.f);
        ushort4 pk0, pk1;
        pk0.x = f2bf(o[0]); pk0.y = f2bf(o[1]); pk0.z = f2bf(o[2]); pk0.w = f2bf(o[3]);
        pk1.x = f2bf(o[4]); pk1.y = f2bf(o[5]); pk1.z = f2bf(o[6]); pk1.w = f2bf(o[7]);
        unsigned short* hp = hbf + (size_t)w * HH + cl * 8;
        *(ushort4*)hp = pk0;
        *(ushort4*)(hp + 4) = pk1;
    }
}

// ---------------- layer-2 aggregation: wave per (dst, rel-half); ballot-driven ----------------
// aggr[d*8+r] = mean_{e in (d,r)} hbf[src_e]   (zeros when empty)
__global__ void agg_kernel(const int* __restrict__ deg, const int* __restrict__ elist,
                           const unsigned short* __restrict__ hbf,
                           unsigned short* __restrict__ aggr, int Nn) {
    int w = (blockIdx.x * blockDim.x + threadIdx.x) >> 6;
    int d = w >> 1;
    if (d >= Nn) return;
    int half = w & 1;
    int lane = threadIdx.x & 63;
    int qid = lane >> 4, cl = lane & 15;      // quad gathers one 256 B bf16 row
    int dd = min(deg[(size_t)d * DEGSTR], CAP);
    int pk = elist[(size_t)d * CAP + lane];
    int myrel = (lane < dd) ? (int)((unsigned)pk >> 27) : 8;

#define ACC8(V, S)                                                 \
    {                                                              \
        S[0] += u2f(V.x << 16); S[1] += u2f(V.x & 0xFFFF0000u);    \
        S[2] += u2f(V.y << 16); S[3] += u2f(V.y & 0xFFFF0000u);    \
        S[4] += u2f(V.z << 16); S[5] += u2f(V.z & 0xFFFF0000u);    \
        S[6] += u2f(V.w << 16); S[7] += u2f(V.w & 0xFFFF0000u);    \
    }

#pragma unroll
    for (int ri = 0; ri < 4; ++ri) {
        int r = half * 4 + ri;
        unsigned long long m = __ballot(myrel == r);
        int c = __popcll(m);
        float inv = 1.0f / fmaxf(1.0f, (float)c);
        float s[8] = {0.f, 0.f, 0.f, 0.f, 0.f, 0.f, 0.f, 0.f};
        int idx = 0;
        while (m) {                            // uniform mask walk; quad (idx&3) loads
            int j = __ffsll((unsigned long long)m) - 1;
            m &= m - 1;
            int pkj = __shfl(pk, j);           // uniform src lane, all lanes active
            if ((idx & 3) == qid) {
                int ss = pkj & SRCMASK;
                uint4 v = *(const uint4*)(hbf + (size_t)ss * HH + cl * 8);
                ACC8(v, s);
            }
            ++idx;
        }
#pragma unroll
        for (int k = 0; k < 8; ++k) {
            s[k] += __shfl_xor(s[k], 16);
            s[k] += __shfl_xor(s[k], 32);
        }
        if (qid == 0) {
            ushort4 p0, p1;
            p0.x = f2bf(s[0] * inv); p0.y = f2bf(s[1] * inv);
            p0.z = f2bf(s[2] * inv); p0.w = f2bf(s[3] * inv);
            p1.x = f2bf(s[4] * inv); p1.y = f2bf(s[5] * inv);
            p1.z = f2bf(s[6] * inv); p1.w = f2bf(s[7] * inv);
            unsigned short* ap = aggr + ((size_t)d * RNUM + r) * HH + cl * 8;
            *(ushort4*)ap = p0;
            *(ushort4*)(ap + 4) = p1;
        }
    }
#undef ACC8
}

// ---------------- GEMM over 9 K-chunks (streaming A) + fused final linear ----------------
__global__ __launch_bounds__(256, 3) void gemm9_kernel(
    const unsigned short* __restrict__ hbf, const unsigned short* __restrict__ aggr,
    const unsigned short* __restrict__ Bt, const float* __restrict__ b2,
    const float* __restrict__ lin_w, const float* __restrict__ lin_b,
    float* __restrict__ out, int Nn) {
    __shared__ unsigned short As[64 * LDA];
    __shared__ unsigned short Bs[128 * LDA];
    const int tid = threadIdx.x;
    const int lane = tid & 63, wv = tid >> 6;
    const int quad = lane >> 4, l16 = lane & 15;
    const int mr = wv & 1, nc = wv >> 1;
    const int m0 = blockIdx.x * 64;

    floatx4 acc[2][4];
#pragma unroll
    for (int a = 0; a < 2; ++a)
#pragma unroll
        for (int bb = 0; bb < 4; ++bb) acc[a][bb] = (floatx4){0.f, 0.f, 0.f, 0.f};

    for (int c = 0; c < 9; ++c) {
        __syncthreads();
        const unsigned short* Bsrc = Bt + (size_t)c * HH * HH;
#pragma unroll
        for (int it = 0; it < 8; ++it) {
            int id = tid + it * 256;
            int rw = id >> 4, c8 = id & 15;
            *(uint4*)(Bs + rw * LDA + c8 * 8) = *(const uint4*)(Bsrc + rw * HH + c8 * 8);
        }
#pragma unroll
        for (int it = 0; it < 4; ++it) {
            int id = tid + it * 256;
            int rw = id >> 4, c8 = id & 15;
            uint4 v = make_uint4(0, 0, 0, 0);
            if (m0 + rw < Nn) {
                const unsigned short* Asrc =
                    (c == 0) ? (hbf + (size_t)(m0 + rw) * HH)
                             : (aggr + ((size_t)(m0 + rw) * RNUM + (c - 1)) * HH);
                v = *(const uint4*)(Asrc + c8 * 8);
            }
            *(uint4*)(As + rw * LDA + c8 * 8) = v;
        }
        __syncthreads();
#pragma unroll
        for (int ks = 0; ks < 4; ++ks) {
            short8 a0 = *(const short8*)(As + (mr * 32 + l16) * LDA + ks * 32 + quad * 8);
            short8 a1 = *(const short8*)(As + (mr * 32 + 16 + l16) * LDA + ks * 32 + quad * 8);
#pragma unroll
            for (int nf = 0; nf < 4; ++nf) {
                short8 b = *(const short8*)(Bs + (nc * 64 + nf * 16 + l16) * LDA + ks * 32 + quad * 8);
                acc[0][nf] = __builtin_amdgcn_mfma_f32_16x16x32_bf16(a0, b, acc[0][nf], 0, 0, 0);
                acc[1][nf] = __builtin_amdgcn_mfma_f32_16x16x32_bf16(a1, b, acc[1][nf], 0, 0, 0);
            }
        }
    }

    // epilogue 1: relu(C + b2) -> As as bf16 (C/D layout: col=lane&15, row=quad*4+reg)
    __syncthreads();
#pragma unroll
    for (int mf = 0; mf < 2; ++mf)
#pragma unroll
        for (int nf = 0; nf < 4; ++nf) {
            int gcol = nc * 64 + nf * 16 + l16;
            float bb = b2[gcol];
#pragma unroll
            for (int rg = 0; rg < 4; ++rg) {
                int row = mr * 32 + mf * 16 + quad * 4 + rg;
                float v = fmaxf(acc[mf][nf][rg] + bb, 0.f);
                As[row * LDA + gcol] = f2bf(v);
            }
        }
    // stage lin_w^T (bf16) into Bs rows 0..39
    for (int it = 0; it < 20; ++it) {
        int id = tid + it * 256;
        int n = id >> 7, k = id & 127;
        Bs[n * LDA + k] = f2bf(lin_w[k * CC + n]);
    }
    __syncthreads();

    floatx4 acc2[3];
#pragma unroll
    for (int nf = 0; nf < 3; ++nf) acc2[nf] = (floatx4){0.f, 0.f, 0.f, 0.f};
#pragma unroll
    for (int ks = 0; ks < 4; ++ks) {
        short8 a = *(const short8*)(As + (wv * 16 + l16) * LDA + ks * 32 + quad * 8);
#pragma unroll
        for (int nf = 0; nf < 3; ++nf) {
            short8 b = *(const short8*)(Bs + (nf * 16 + l16) * LDA + ks * 32 + quad * 8);
            acc2[nf] = __builtin_amdgcn_mfma_f32_16x16x32_bf16(a, b, acc2[nf], 0, 0, 0);
        }
    }
#pragma unroll
    for (int nf = 0; nf < 3; ++nf) {
        int col = nf * 16 + l16;
        if (col < CC) {
            float lb = lin_b[col];
#pragma unroll
            for (int rg = 0; rg < 4; ++rg) {
                int grow = m0 + wv * 16 + quad * 4 + rg;
                if (grow < Nn) out[(size_t)grow * CC + col] = acc2[nf][rg] + lb;
            }
        }
    }
}

// ---------------- launcher ----------------

extern "C" void kernel_launch(void* const* d_in, const int* in_sizes, int n_in,
                              void* d_out, int out_size, void* d_ws, size_t ws_size,
                              hipStream_t stream) {
    const int* ei      = (const int*)d_in[0];
    const int* et      = (const int*)d_in[1];
    const float* W1    = (const float*)d_in[2];
    const float* root1 = (const float*)d_in[3];
    const float* b1    = (const float*)d_in[4];
    const float* W2    = (const float*)d_in[5];
    const float* root2 = (const float*)d_in[6];
    const float* b2    = (const float*)d_in[7];
    const float* lw    = (const float*)d_in[8];
    const float* lb    = (const float*)d_in[9];
    float* out = (float*)d_out;

    const int E = in_sizes[1];
    const int N = in_sizes[3] / HH;

    // ws: deg[N*16] | elist[N*CAP] ints; then hbf | W1b | Bt | aggr (bf16)
    int* deg   = (int*)d_ws;
    int* elist = deg + (size_t)N * DEGSTR;
    size_t iofs = (size_t)N * DEGSTR + (size_t)N * CAP;
    iofs = (iofs + 3) & ~(size_t)3;                     // 16B align
    unsigned short* hbf  = (unsigned short*)((int*)d_ws + iofs);
    unsigned short* W1b  = hbf + (size_t)N * HH;
    unsigned short* Bt   = W1b + (size_t)N * RNUM * HH;
    unsigned short* aggr = Bt + (size_t)9 * HH * HH;

    const int* src = ei;
    const int* dst = ei + E;

    const size_t castElems = (size_t)N * RNUM * HH;
    const int fillB = (E + 255) / 256;
    const int castB = (int)((castElems / 8 + 255) / 256);

    hipMemsetAsync(deg, 0, (size_t)N * DEGSTR * sizeof(int), stream);
    prep_kernel<<<fillB + castB + 9 * 32, 256, 0, stream>>>(
        src, dst, et, deg, elist, E, W1, W1b, castElems, root2, W2, Bt, fillB, castB);

    gather1_kernel<<<(N * 64 + 255) / 256, 256, 0, stream>>>(deg, elist, W1b, root1, b1, hbf, N);
    agg_kernel<<<(N * 2 * 64 + 255) / 256, 256, 0, stream>>>(deg, elist, hbf, aggr, N);
    gemm9_kernel<<<(N + 63) / 64, 256, 0, stream>>>(hbf, aggr, Bt, b2, lw, lb, out, N);
}

// Round 4
// 480.458 us; speedup vs baseline: 1.1840x; 1.1620x over previous
//
#include <hip/hip_runtime.h>

#define HH 128
#define RNUM 8
#define CC 40
#define CAP 64                // padded edge slots per dst (P(deg>64) ~ 1e-19)
#define LDA 136               // LDS row stride (bf16): 128 + 8 pad
#define SRCMASK 0x7FFFFFF
#define DEGSTR 16             // deg counter stride in ints: 1 counter per 64-B line

typedef __attribute__((ext_vector_type(8))) short short8;
typedef __attribute__((ext_vector_type(4))) float floatx4;

__device__ __forceinline__ float u2f(unsigned u) {
    union { unsigned u; float f; } c;
    c.u = u;
    return c.f;
}
__device__ __forceinline__ unsigned short f2bf(float f) {
    union { float f; unsigned u; } c;
    c.f = f;
    return (unsigned short)((c.u + 0x7FFFu + ((c.u >> 16) & 1u)) >> 16);
}

// ---------------- edge bucketing: elist[d*64+p] = (rel<<27)|src ----------------
__global__ void fill_kernel(const int* __restrict__ src, const int* __restrict__ dst,
                            const int* __restrict__ et, int* __restrict__ deg,
                            int* __restrict__ elist, int E) {
    int e = blockIdx.x * blockDim.x + threadIdx.x;
    if (e < E) {
        int d = dst[e];
        int p = atomicAdd(&deg[(size_t)d * DEGSTR], 1);
        if (p < CAP) elist[(size_t)d * CAP + p] = (int)(((unsigned)et[e] << 27) | (unsigned)src[e]);
    }
}

// ---------------- Bt[c][n][k] = bf16(Bc[k][n]), c0=root2, c1..8=W2[r] ----------------
__global__ void tcast_kernel(const float* __restrict__ root2, const float* __restrict__ W2,
                             unsigned short* __restrict__ Bt) {
    int bid = blockIdx.x;
    int c = bid >> 5;
    int id = (bid & 31) * 256 + threadIdx.x;
    int n = id >> 6, kp = id & 63;
    const float* B = (c == 0) ? root2 : W2 + (size_t)(c - 1) * HH * HH;
    float g0 = B[(2 * kp) * HH + n];
    float g1 = B[(2 * kp + 1) * HH + n];
    unsigned v = (unsigned)f2bf(g0) | ((unsigned)f2bf(g1) << 16);
    *(unsigned*)(Bt + (size_t)c * HH * HH + n * HH + 2 * kp) = v;
}

// ---------------- layer 1: wave per dst; fp32 W1 gather ----------------
// h[d] = relu( sum_r (1/c_r) * sum_{e in (d,r)} W1[r, src_e] + root1[d] + b1 )
__global__ void gather1_kernel(const int* __restrict__ deg, const int* __restrict__ elist,
                               const float* __restrict__ W1, const float* __restrict__ root1,
                               const float* __restrict__ b1, unsigned short* __restrict__ hbf,
                               int Nn) {
    int w = (blockIdx.x * blockDim.x + threadIdx.x) >> 6;
    if (w >= Nn) return;
    int lane = threadIdx.x & 63;
    int qid = lane >> 4, cl = lane & 15;      // quad gathers one 512 B fp32 row
    int dd = min(deg[(size_t)w * DEGSTR], CAP);
    int pk = elist[(size_t)w * CAP + lane];   // one coalesced 256 B load: slot per lane
    int myrel = (lane < dd) ? (int)((unsigned)pk >> 27) : 8;

    // per-relation counts via ballot; lane r holds 1/max(1,c_r)
    float myinv = 1.0f;
#pragma unroll
    for (int r = 0; r < 8; ++r) {
        unsigned long long m = __ballot(myrel == r);
        int c = __popcll(m);
        if (lane == r) myinv = 1.0f / fmaxf(1.0f, (float)c);
    }

    float s0[8] = {0.f, 0.f, 0.f, 0.f, 0.f, 0.f, 0.f, 0.f};
    float s1[8] = {0.f, 0.f, 0.f, 0.f, 0.f, 0.f, 0.f, 0.f};
    float s2[8] = {0.f, 0.f, 0.f, 0.f, 0.f, 0.f, 0.f, 0.f};
    float s3[8] = {0.f, 0.f, 0.f, 0.f, 0.f, 0.f, 0.f, 0.f};

#define GRP(G, S)                                                                 \
    {                                                                             \
        int j = ((G) << 2) + qid;                                                 \
        int jj = min(j, dd - 1);                                                  \
        int pkj = __shfl(pk, jj);                                                 \
        int rr = (int)((unsigned)pkj >> 27);                                      \
        float wt = __shfl(myinv, rr);                                             \
        int ss = pkj & SRCMASK;                                                   \
        const float* p = W1 + ((size_t)rr * Nn + ss) * HH + cl * 8;               \
        if (j < dd) {                                                             \
            float4 v0 = *(const float4*)p;                                        \
            float4 v1 = *(const float4*)(p + 4);                                  \
            S[0] += v0.x * wt; S[1] += v0.y * wt; S[2] += v0.z * wt; S[3] += v0.w * wt; \
            S[4] += v1.x * wt; S[5] += v1.y * wt; S[6] += v1.z * wt; S[7] += v1.w * wt; \
        }                                                                         \
    }

    int ng = (dd + 3) >> 2;                   // number of 4-edge groups (uniform)
    int g = 0;
    for (; g + 3 < ng; g += 4) {              // 4 streams -> 8 loads in flight/lane
        GRP(g, s0);
        GRP(g + 1, s1);
        GRP(g + 2, s2);
        GRP(g + 3, s3);
    }
    for (; g < ng; ++g) GRP(g, s0);
#undef GRP

#pragma unroll
    for (int k = 0; k < 8; ++k) {
        s0[k] += s1[k] + s2[k] + s3[k];
        s0[k] += __shfl_xor(s0[k], 16);
        s0[k] += __shfl_xor(s0[k], 32);
    }

    if (qid == 0) {
        const float* rp = root1 + (size_t)w * HH + cl * 8;
        float4 r0 = *(const float4*)rp;
        float4 r1 = *(const float4*)(rp + 4);
        float4 c0 = *(const float4*)(b1 + cl * 8);
        float4 c1 = *(const float4*)(b1 + cl * 8 + 4);
        float o[8];
        o[0] = fmaxf(s0[0] + r0.x + c0.x, 0.f); o[1] = fmaxf(s0[1] + r0.y + c0.y, 0.f);
        o[2] = fmaxf(s0[2] + r0.z + c0.z, 0.f); o[3] = fmaxf(s0[3] + r0.w + c0.w, 0.f);
        o[4] = fmaxf(s0[4] + r1.x + c1.x, 0.f); o[5] = fmaxf(s0[5] + r1.y + c1.y, 0.f);
        o[6] = fmaxf(s0[6] + r1.z + c1.z, 0.f); o[7] = fmaxf(s0[7] + r1.w + c1.w, 0.f);
        ushort4 pk0, pk1;
        pk0.x = f2bf(o[0]); pk0.y = f2bf(o[1]); pk0.z = f2bf(o[2]); pk0.w = f2bf(o[3]);
        pk1.x = f2bf(o[4]); pk1.y = f2bf(o[5]); pk1.z = f2bf(o[6]); pk1.w = f2bf(o[7]);
        unsigned short* hp = hbf + (size_t)w * HH + cl * 8;
        *(ushort4*)hp = pk0;
        *(ushort4*)(hp + 4) = pk1;
    }
}

// ---------------- dense transform: xrb[c][n][:] = bf16( h[n] @ Bc ), c=0..8 ----------------
// grid = nmb * 9 blocks; block = (m-tile of 64 rows, one c)
__global__ __launch_bounds__(256, 3) void gemmxr_kernel(
    const unsigned short* __restrict__ hbf, const unsigned short* __restrict__ Bt,
    unsigned short* __restrict__ xrb, int Nn, int nmb) {
    __shared__ unsigned short As[64 * LDA];
    __shared__ unsigned short Bs[128 * LDA];
    const int tid = threadIdx.x;
    const int lane = tid & 63, wv = tid >> 6;          // 4 waves
    const int quad = lane >> 4, l16 = lane & 15;
    const int mr = wv & 1, nc = wv >> 1;               // 2x2 wave tiling
    const int mb = blockIdx.x % nmb;
    const int c = blockIdx.x / nmb;
    const int m0 = mb * 64;

    // stage A tile (64 x 128 bf16) once
#pragma unroll
    for (int it = 0; it < 4; ++it) {
        int id = tid + it * 256;
        int rw = id >> 4, c8 = id & 15;
        uint4 v = make_uint4(0, 0, 0, 0);
        if (m0 + rw < Nn) v = *(const uint4*)(hbf + (size_t)(m0 + rw) * HH + c8 * 8);
        *(uint4*)(As + rw * LDA + c8 * 8) = v;
    }
    // stage B (128 x 128 bf16)
    const unsigned short* Bsrc = Bt + (size_t)c * HH * HH;
#pragma unroll
    for (int it = 0; it < 8; ++it) {
        int id = tid + it * 256;
        int rw = id >> 4, c8 = id & 15;
        *(uint4*)(Bs + rw * LDA + c8 * 8) = *(const uint4*)(Bsrc + rw * HH + c8 * 8);
    }
    __syncthreads();

    floatx4 acc[2][4];
#pragma unroll
    for (int a = 0; a < 2; ++a)
#pragma unroll
        for (int bb = 0; bb < 4; ++bb) acc[a][bb] = (floatx4){0.f, 0.f, 0.f, 0.f};

#pragma unroll
    for (int ks = 0; ks < 4; ++ks) {
        short8 a0 = *(const short8*)(As + (mr * 32 + l16) * LDA + ks * 32 + quad * 8);
        short8 a1 = *(const short8*)(As + (mr * 32 + 16 + l16) * LDA + ks * 32 + quad * 8);
#pragma unroll
        for (int nf = 0; nf < 4; ++nf) {
            short8 b = *(const short8*)(Bs + (nc * 64 + nf * 16 + l16) * LDA + ks * 32 + quad * 8);
            acc[0][nf] = __builtin_amdgcn_mfma_f32_16x16x32_bf16(a0, b, acc[0][nf], 0, 0, 0);
            acc[1][nf] = __builtin_amdgcn_mfma_f32_16x16x32_bf16(a1, b, acc[1][nf], 0, 0, 0);
        }
    }

    // pack acc -> Bs rows 0..63 (Bs free now), then coalesced store
    __syncthreads();
#pragma unroll
    for (int mf = 0; mf < 2; ++mf)
#pragma unroll
        for (int nf = 0; nf < 4; ++nf) {
            int gcol = nc * 64 + nf * 16 + l16;
#pragma unroll
            for (int rg = 0; rg < 4; ++rg) {
                int row = mr * 32 + mf * 16 + quad * 4 + rg;
                Bs[row * LDA + gcol] = f2bf(acc[mf][nf][rg]);
            }
        }
    __syncthreads();
#pragma unroll
    for (int it = 0; it < 4; ++it) {
        int id = tid + it * 256;
        int rw = id >> 4, c8 = id & 15;
        if (m0 + rw < Nn)
            *(uint4*)(xrb + ((size_t)c * Nn + m0 + rw) * HH + c8 * 8) =
                *(const uint4*)(Bs + rw * LDA + c8 * 8);
    }
}

// ---------------- layer 2: wave per dst; bf16 xr gather + self + b2 + relu ----------------
// h2[d] = relu( sum_r (1/c_r) sum_{e in (d,r)} xr[rel+1][src_e] + xr[0][d] + b2 )
__global__ void gather2_kernel(const int* __restrict__ deg, const int* __restrict__ elist,
                               const unsigned short* __restrict__ xrb, const float* __restrict__ b2,
                               unsigned short* __restrict__ h2bf, int Nn) {
    int w = (blockIdx.x * blockDim.x + threadIdx.x) >> 6;
    if (w >= Nn) return;
    int lane = threadIdx.x & 63;
    int qid = lane >> 4, cl = lane & 15;      // quad gathers one 256 B bf16 row
    int dd = min(deg[(size_t)w * DEGSTR], CAP);
    int pk = elist[(size_t)w * CAP + lane];
    int myrel = (lane < dd) ? (int)((unsigned)pk >> 27) : 8;

    float myinv = 1.0f;
#pragma unroll
    for (int r = 0; r < 8; ++r) {
        unsigned long long m = __ballot(myrel == r);
        int c = __popcll(m);
        if (lane == r) myinv = 1.0f / fmaxf(1.0f, (float)c);
    }

    float s0[8] = {0.f, 0.f, 0.f, 0.f, 0.f, 0.f, 0.f, 0.f};
    float s1[8] = {0.f, 0.f, 0.f, 0.f, 0.f, 0.f, 0.f, 0.f};
    float s2[8] = {0.f, 0.f, 0.f, 0.f, 0.f, 0.f, 0.f, 0.f};
    float s3[8] = {0.f, 0.f, 0.f, 0.f, 0.f, 0.f, 0.f, 0.f};

#define GRP(G, S)                                                                 \
    {                                                                             \
        int j = ((G) << 2) + qid;                                                 \
        int jj = min(j, dd - 1);                                                  \
        int pkj = __shfl(pk, jj);                                                 \
        int rr = (int)((unsigned)pkj >> 27);                                      \
        float wt = __shfl(myinv, rr);                                             \
        int ss = pkj & SRCMASK;                                                   \
        const unsigned short* p = xrb + ((size_t)(rr + 1) * Nn + ss) * HH + cl * 8; \
        if (j < dd) {                                                             \
            uint4 v = *(const uint4*)p;                                           \
            S[0] += u2f(v.x << 16) * wt; S[1] += u2f(v.x & 0xFFFF0000u) * wt;     \
            S[2] += u2f(v.y << 16) * wt; S[3] += u2f(v.y & 0xFFFF0000u) * wt;     \
            S[4] += u2f(v.z << 16) * wt; S[5] += u2f(v.z & 0xFFFF0000u) * wt;     \
            S[6] += u2f(v.w << 16) * wt; S[7] += u2f(v.w & 0xFFFF0000u) * wt;     \
        }                                                                         \
    }

    int ng = (dd + 3) >> 2;
    int g = 0;
    for (; g + 3 < ng; g += 4) {
        GRP(g, s0);
        GRP(g + 1, s1);
        GRP(g + 2, s2);
        GRP(g + 3, s3);
    }
    for (; g < ng; ++g) GRP(g, s0);
#undef GRP

#pragma unroll
    for (int k = 0; k < 8; ++k) {
        s0[k] += s1[k] + s2[k] + s3[k];
        s0[k] += __shfl_xor(s0[k], 16);
        s0[k] += __shfl_xor(s0[k], 32);
    }

    if (qid == 0) {
        // self term xr[0][w] (bf16) + b2 (fp32)
        uint4 sv = *(const uint4*)(xrb + (size_t)w * HH + cl * 8);
        float4 c0 = *(const float4*)(b2 + cl * 8);
        float4 c1 = *(const float4*)(b2 + cl * 8 + 4);
        float o[8];
        o[0] = fmaxf(s0[0] + u2f(sv.x << 16) + c0.x, 0.f);
        o[1] = fmaxf(s0[1] + u2f(sv.x & 0xFFFF0000u) + c0.y, 0.f);
        o[2] = fmaxf(s0[2] + u2f(sv.y << 16) + c0.z, 0.f);
        o[3] = fmaxf(s0[3] + u2f(sv.y & 0xFFFF0000u) + c0.w, 0.f);
        o[4] = fmaxf(s0[4] + u2f(sv.z << 16) + c1.x, 0.f);
        o[5] = fmaxf(s0[5] + u2f(sv.z & 0xFFFF0000u) + c1.y, 0.f);
        o[6] = fmaxf(s0[6] + u2f(sv.w << 16) + c1.z, 0.f);
        o[7] = fmaxf(s0[7] + u2f(sv.w & 0xFFFF0000u) + c1.w, 0.f);
        ushort4 p0, p1;
        p0.x = f2bf(o[0]); p0.y = f2bf(o[1]); p0.z = f2bf(o[2]); p0.w = f2bf(o[3]);
        p1.x = f2bf(o[4]); p1.y = f2bf(o[5]); p1.z = f2bf(o[6]); p1.w = f2bf(o[7]);
        unsigned short* hp = h2bf + (size_t)w * HH + cl * 8;
        *(ushort4*)hp = p0;
        *(ushort4*)(hp + 4) = p1;
    }
}

// ---------------- final linear: out = h2 @ lin_w + lin_b ----------------
__global__ __launch_bounds__(256, 4) void linout_kernel(
    const unsigned short* __restrict__ h2, const float* __restrict__ lin_w,
    const float* __restrict__ lin_b, float* __restrict__ out, int Nn) {
    __shared__ unsigned short As[64 * LDA];
    __shared__ unsigned short Bs[48 * LDA];
    const int tid = threadIdx.x;
    const int lane = tid & 63, wv = tid >> 6;
    const int quad = lane >> 4, l16 = lane & 15;
    const int m0 = blockIdx.x * 64;

#pragma unroll
    for (int it = 0; it < 4; ++it) {
        int id = tid + it * 256;
        int rw = id >> 4, c8 = id & 15;
        uint4 v = make_uint4(0, 0, 0, 0);
        if (m0 + rw < Nn) v = *(const uint4*)(h2 + (size_t)(m0 + rw) * HH + c8 * 8);
        *(uint4*)(As + rw * LDA + c8 * 8) = v;
    }
    // stage lin_w^T (bf16) rows 0..47 (rows >= CC zeroed)
#pragma unroll
    for (int it = 0; it < 24; ++it) {
        int id = tid + it * 256;
        int n = id >> 7, k = id & 127;
        Bs[n * LDA + k] = (n < CC) ? f2bf(lin_w[(size_t)k * CC + n]) : (unsigned short)0;
    }
    __syncthreads();

    floatx4 acc2[3];
#pragma unroll
    for (int nf = 0; nf < 3; ++nf) acc2[nf] = (floatx4){0.f, 0.f, 0.f, 0.f};
#pragma unroll
    for (int ks = 0; ks < 4; ++ks) {
        short8 a = *(const short8*)(As + (wv * 16 + l16) * LDA + ks * 32 + quad * 8);
#pragma unroll
        for (int nf = 0; nf < 3; ++nf) {
            short8 b = *(const short8*)(Bs + (nf * 16 + l16) * LDA + ks * 32 + quad * 8);
            acc2[nf] = __builtin_amdgcn_mfma_f32_16x16x32_bf16(a, b, acc2[nf], 0, 0, 0);
        }
    }
#pragma unroll
    for (int nf = 0; nf < 3; ++nf) {
        int col = nf * 16 + l16;
        if (col < CC) {
            float lb = lin_b[col];
#pragma unroll
            for (int rg = 0; rg < 4; ++rg) {
                int grow = m0 + wv * 16 + quad * 4 + rg;
                if (grow < Nn) out[(size_t)grow * CC + col] = acc2[nf][rg] + lb;
            }
        }
    }
}

// ---------------- launcher ----------------

extern "C" void kernel_launch(void* const* d_in, const int* in_sizes, int n_in,
                              void* d_out, int out_size, void* d_ws, size_t ws_size,
                              hipStream_t stream) {
    const int* ei      = (const int*)d_in[0];
    const int* et      = (const int*)d_in[1];
    const float* W1    = (const float*)d_in[2];
    const float* root1 = (const float*)d_in[3];
    const float* b1    = (const float*)d_in[4];
    const float* W2    = (const float*)d_in[5];
    const float* root2 = (const float*)d_in[6];
    const float* b2    = (const float*)d_in[7];
    const float* lw    = (const float*)d_in[8];
    const float* lb    = (const float*)d_in[9];
    float* out = (float*)d_out;

    const int E = in_sizes[1];
    const int N = in_sizes[3] / HH;

    // ws: deg[N*16] | elist[N*CAP] ints; then hbf | Bt | xrb[9*N*H] | h2 (bf16)
    int* deg   = (int*)d_ws;
    int* elist = deg + (size_t)N * DEGSTR;
    size_t iofs = (size_t)N * DEGSTR + (size_t)N * CAP;
    iofs = (iofs + 3) & ~(size_t)3;                     // 16B align
    unsigned short* hbf  = (unsigned short*)((int*)d_ws + iofs);
    unsigned short* Bt   = hbf + (size_t)N * HH;
    unsigned short* xrb  = Bt + (size_t)9 * HH * HH;
    unsigned short* h2bf = xrb + (size_t)9 * N * HH;

    const int* src = ei;
    const int* dst = ei + E;

    const int nmb = (N + 63) / 64;

    hipMemsetAsync(deg, 0, (size_t)N * DEGSTR * sizeof(int), stream);
    fill_kernel<<<(E + 255) / 256, 256, 0, stream>>>(src, dst, et, deg, elist, E);
    tcast_kernel<<<9 * 32, 256, 0, stream>>>(root2, W2, Bt);
    gather1_kernel<<<(N * 64 + 255) / 256, 256, 0, stream>>>(deg, elist, W1, root1, b1, hbf, N);
    gemmxr_kernel<<<nmb * 9, 256, 0, stream>>>(hbf, Bt, xrb, N, nmb);
    gather2_kernel<<<(N * 64 + 255) / 256, 256, 0, stream>>>(deg, elist, xrb, b2, h2bf, N);
    linout_kernel<<<nmb, 256, 0, stream>>>(h2bf, lw, lb, out, N);
}